// Round 1
// baseline (88.736 us; speedup 1.0000x reference)
//
#include <hip/hip_runtime.h>
#include <math.h>

#define HDIM   512
#define NH     32
#define NP     16                 // mode pairs
#define LLEN   8192
#define BLOCK  256
#define LSPLIT 2
#define LPB    (LLEN / LSPLIT)    // 4096 l per block
#define LPT    16                 // consecutive l per thread

// ---- workspace layout (float offsets) ----
// gA : [512][16 pairs][16 k] float4 {rea,reb,ima,imb} = 2*Cs*w^(16k)
// gB : [2 ls][512][16][16] float4                     = w^(4096*ls + 256*k)
// gW / gPQ / gP2 : [512][16] float4
#define OFF_A   0
#define OFF_B   524288            // 512*256*4
#define OFF_W   1572864           // OFF_B + 2*512*256*4
#define OFF_PQ  1605632
#define OFF_P2  1638400
// total 1671168 floats = 6.7 MB  (ws is 256 MiB per the harness poison)

typedef float vf2 __attribute__((ext_vector_type(2)));

static __device__ inline vf2 pk_mul(vf2 a, vf2 b) {
    vf2 d; asm("v_pk_mul_f32 %0, %1, %2" : "=v"(d) : "v"(a), "v"(b)); return d;
}
static __device__ inline vf2 pk_add(vf2 a, vf2 b) {
    vf2 d; asm("v_pk_add_f32 %0, %1, %2" : "=v"(d) : "v"(a), "v"(b)); return d;
}
static __device__ inline vf2 pk_fma(vf2 a, vf2 b, vf2 c) {   // a*b + c
    vf2 d; asm("v_pk_fma_f32 %0, %1, %2, %3" : "=v"(d) : "v"(a), "v"(b), "v"(c)); return d;
}
static __device__ inline vf2 pk_fms(vf2 a, vf2 b, vf2 c) {   // a*b - c
    vf2 d; asm("v_pk_fma_f32 %0, %1, %2, %3 neg_lo:[0,0,1] neg_hi:[0,0,1]"
               : "=v"(d) : "v"(a), "v"(b), "v"(c)); return d;
}

// ---------------------------------------------------------------------------
// Kernel 1: fp64 table build. One thread per (h, n, walk), walk in {A, B0, B1}.
// Only ONE sincos + ONE exp per thread; all powers via fp64 repeated squaring.
// 512*32*3 = 49152 threads = 192 blocks.
// ---------------------------------------------------------------------------
__global__ __launch_bounds__(256) void s4d_tables(
    const float* __restrict__ C,          // (H, NH, 2)
    const float* __restrict__ log_dt,     // (H,)
    const float* __restrict__ log_A_real, // (H, NH)
    const float* __restrict__ A_imag,     // (H, NH)
    float* __restrict__ ws)
{
    const int gid = blockIdx.x * 256 + threadIdx.x;
    if (gid >= HDIM * NH * 3) return;
    const int h    = gid / 96;            // 96 = NH*3
    const int r    = gid - h * 96;
    const int n    = r & 31;
    const int walk = r >> 5;              // 0 = tabA+consts, 1 = tabB ls0, 2 = tabB ls1
    const int P = n >> 1, o = n & 1;

    const double dt  = exp((double)log_dt[h]);
    const double Are = -exp((double)log_A_real[h * NH + n]);
    const double Aim = (double)A_imag[h * NH + n];
    const double dre = Are * dt, dim = Aim * dt;

    double s1, c1; sincos(dim, &s1, &c1);
    const double em = exp(dre);
    const double wr = em * c1, wi = em * s1;      // w = exp(dtA)

    // w^16 via 4 squarings
    double xr = wr, xi = wi;
#pragma unroll
    for (int j = 0; j < 4; ++j) { const double t = xr*xr - xi*xi; xi = 2.0*xr*xi; xr = t; }

    float* gA  = ws + OFF_A;
    float* gB  = ws + OFF_B;
    float* gW  = ws + OFF_W;
    float* gPQ = ws + OFF_PQ;
    float* gP2 = ws + OFF_P2;

    if (walk == 0) {
        // per-pair constants
        const double p  = 2.0 * wr;
        const double q  = em * em;
        const double p2 = 2.0 * (wr * wr - wi * wi);
        const double q2 = q * q;
        gW [(h*16 + P)*4 + o]     = (float)wr;
        gW [(h*16 + P)*4 + 2 + o] = (float)wi;
        gPQ[(h*16 + P)*4 + o]     = (float)p;
        gPQ[(h*16 + P)*4 + 2 + o] = (float)q;
        gP2[(h*16 + P)*4 + o]     = (float)p2;
        gP2[(h*16 + P)*4 + 2 + o] = (float)q2;

        // 2*C_scaled
        const double nre = wr - 1.0, nim = wi;
        const double inv = 1.0 / (Are * Are + Aim * Aim);
        const double fre = (nre * Are + nim * Aim) * inv;
        const double fim = (nim * Are - nre * Aim) * inv;
        const double Cre = (double)C[(h * NH + n) * 2 + 0];
        const double Cim = (double)C[(h * NH + n) * 2 + 1];
        double gr = 2.0 * (Cre * fre - Cim * fim);
        double gi = 2.0 * (Cre * fim + Cim * fre);
        // walk: gA[h][P][k] = 2Cs * w^(16k)
        for (int k = 0; k < 16; ++k) {
            const int idx = (h * 256 + P * 16 + k) * 4;
            gA[idx + o]     = (float)gr;
            gA[idx + 2 + o] = (float)gi;
            const double t = gr * xr - gi * xi;
            gi = gr * xi + gi * xr; gr = t;
        }
    } else {
        // w^256 = (w^16)^16 via 4 more squarings
#pragma unroll
        for (int j = 0; j < 4; ++j) { const double t = xr*xr - xi*xi; xi = 2.0*xr*xi; xr = t; }
        const int ls = walk - 1;
        double er, ei;
        if (ls == 0) { er = 1.0; ei = 0.0; }
        else {
            // w^4096 = (w^256)^16
            double br = xr, bi = xi;
#pragma unroll
            for (int j = 0; j < 4; ++j) { const double t = br*br - bi*bi; bi = 2.0*br*bi; br = t; }
            er = br; ei = bi;
        }
        // walk: gB[ls][h][P][k] = w^(4096*ls + 256*k)
        for (int k = 0; k < 16; ++k) {
            const int idx = ((ls * 512 + h) * 256 + P * 16 + k) * 4;
            gB[idx + o]     = (float)er;
            gB[idx + 2 + o] = (float)ei;
            const double t = er * xr - ei * xi;
            ei = er * xi + ei * xr; er = t;
        }
    }
}

// ---------------------------------------------------------------------------
// Kernel 2: pure-fp32 main loop. Tables arrive via 2 coalesced float4 loads
// per thread into LDS; structure of the verified recurrence loop unchanged.
// ---------------------------------------------------------------------------
__global__ __launch_bounds__(BLOCK, 4) void s4d_main(
    const float* __restrict__ ws,
    float* __restrict__ out)              // (H, LLEN)
{
    __shared__ float4 tabA[NP + 1][16];   // {Axa,Axb,Aya,Ayb}: 2Cs*exp(dtA*16lo)
    __shared__ float4 tabB[NP + 1][16];   // {Bxa,Bxb,Bya,Byb}: exp(dtA*(LPB*ls+256hi))
    __shared__ float4 s_w [NP + 1];
    __shared__ float4 s_pq[NP + 1];
    __shared__ float4 s_p2[NP + 1];

    const int h   = blockIdx.y;
    const int ls  = blockIdx.x;
    const int tid = threadIdx.x;

    // ---- trivial prologue: global -> LDS ----
    {
        const float4* gA4  = (const float4*)(ws + OFF_A);
        const float4* gB4  = (const float4*)(ws + OFF_B);
        const float4* gW4  = (const float4*)(ws + OFF_W);
        const float4* gPQ4 = (const float4*)(ws + OFF_PQ);
        const float4* gP24 = (const float4*)(ws + OFF_P2);
        ((float4*)&tabA[0][0])[tid] = gA4[h * 256 + tid];
        ((float4*)&tabB[0][0])[tid] = gB4[(ls * 512 + h) * 256 + tid];
        if (tid < 16)      s_w [tid]      = gW4 [h * 16 + tid];
        else if (tid < 32) s_pq[tid - 16] = gPQ4[h * 16 + tid - 16];
        else if (tid < 48) s_p2[tid - 32] = gP24[h * 16 + tid - 32];
    }
    __syncthreads();

    const int lo = tid & 15, hi = tid >> 4;   // 16*tid = 256*hi + 16*lo

    vf2 acc[LPT];
#pragma unroll
    for (int l = 0; l < LPT; ++l) acc[l] = (vf2)(0.f);

    float4 a4 = tabA[0][lo], b4 = tabB[0][hi];
    float4 c0 = s_w[0], c1 = s_pq[0], c2 = s_p2[0];

#pragma unroll 2
    for (int P = 0; P < NP; ++P) {
        // prefetch next pair's LDS data (row NP is padding)
        const float4 na = tabA[P + 1][lo], nb = tabB[P + 1][hi];
        const float4 n0 = s_w[P + 1], n1 = s_pq[P + 1], n2 = s_p2[P + 1];

        const vf2 Ax = {a4.x, a4.y}, Ay = {a4.z, a4.w};
        const vf2 Bx = {b4.x, b4.y}, By = {b4.z, b4.w};
        const vf2 wr = {c0.x, c0.y}, wi = {c0.z, c0.w};
        const vf2 p  = {c1.x, c1.y}, q  = {c1.z, c1.w};
        const vf2 p2 = {c2.x, c2.y}, q2 = {c2.z, c2.w};

        // T = A'.B (Cs folded into A'); seeds y0..y3
        const vf2 Tr = pk_fms(Ax, Bx, pk_mul(Ay, By));
        const vf2 Ti = pk_fma(Ax, By, pk_mul(Ay, Bx));
        const vf2 y0 = Tr;
        const vf2 y1 = pk_fms(Tr, wr, pk_mul(Ti, wi));
        const vf2 y2 = pk_fms(p, y1, pk_mul(q, y0));
        const vf2 y3 = pk_fms(p, y2, pk_mul(q, y1));
        acc[0] = pk_add(acc[0], y0);
        acc[1] = pk_add(acc[1], y1);
        acc[2] = pk_add(acc[2], y2);
        acc[3] = pk_add(acc[3], y3);

        vf2 e0 = y0, e1 = y2, o0 = y1, o1 = y3;
#pragma unroll
        for (int m = 0; m < 6; ++m) {
            const vf2 e2 = pk_fms(p2, e1, pk_mul(q2, e0));
            const vf2 o2 = pk_fms(p2, o1, pk_mul(q2, o0));
            acc[4 + 2 * m] = pk_add(acc[4 + 2 * m], e2);
            acc[5 + 2 * m] = pk_add(acc[5 + 2 * m], o2);
            e0 = e1; e1 = e2;
            o0 = o1; o1 = o2;
        }
        a4 = na; b4 = nb; c0 = n0; c1 = n1; c2 = n2;
    }

    // epilogue: horizontal add over pair lanes, 4x float4 stores
    float* orow = out + (size_t)h * LLEN + ls * LPB + LPT * tid;
#pragma unroll
    for (int j = 0; j < 4; ++j) {
        *(float4*)(orow + 4 * j) = make_float4(
            acc[4*j+0].x + acc[4*j+0].y,
            acc[4*j+1].x + acc[4*j+1].y,
            acc[4*j+2].x + acc[4*j+2].y,
            acc[4*j+3].x + acc[4*j+3].y);
    }
}

extern "C" void kernel_launch(void* const* d_in, const int* in_sizes, int n_in,
                              void* d_out, int out_size, void* d_ws, size_t ws_size,
                              hipStream_t stream) {
    const float* C          = (const float*)d_in[0];
    const float* log_dt     = (const float*)d_in[1];
    const float* log_A_real = (const float*)d_in[2];
    const float* A_imag     = (const float*)d_in[3];
    float* out = (float*)d_out;
    float* ws  = (float*)d_ws;

    s4d_tables<<<192, 256, 0, stream>>>(C, log_dt, log_A_real, A_imag, ws);
    s4d_main<<<dim3(LSPLIT, HDIM), BLOCK, 0, stream>>>(ws, out);
}

// Round 2
// 77.853 us; speedup vs baseline: 1.1398x; 1.1398x over previous
//
#include <hip/hip_runtime.h>
#include <math.h>

#define HDIM   512
#define NH     32
#define NP     16                 // mode pairs
#define LLEN   8192
#define BLOCK  256
#define LSPLIT 2
#define LPB    (LLEN / LSPLIT)    // 4096 l per block
#define LPT    16                 // consecutive l per thread

typedef float vf2 __attribute__((ext_vector_type(2)));

// guaranteed packed fp32 (VOP3P), 64-bit VGPR-pair operands
static __device__ inline vf2 pk_mul(vf2 a, vf2 b) {
    vf2 d; asm("v_pk_mul_f32 %0, %1, %2" : "=v"(d) : "v"(a), "v"(b)); return d;
}
static __device__ inline vf2 pk_add(vf2 a, vf2 b) {
    vf2 d; asm("v_pk_add_f32 %0, %1, %2" : "=v"(d) : "v"(a), "v"(b)); return d;
}
static __device__ inline vf2 pk_fma(vf2 a, vf2 b, vf2 c) {   // a*b + c
    vf2 d; asm("v_pk_fma_f32 %0, %1, %2, %3" : "=v"(d) : "v"(a), "v"(b), "v"(c)); return d;
}
static __device__ inline vf2 pk_fms(vf2 a, vf2 b, vf2 c) {   // a*b - c
    vf2 d; asm("v_pk_fma_f32 %0, %1, %2, %3 neg_lo:[0,0,1] neg_hi:[0,0,1]"
               : "=v"(d) : "v"(a), "v"(b), "v"(c)); return d;
}

// fp64 complex helpers for the prologue power ladder
static __device__ inline void csq(double& r, double& i) {
    const double t = r * r - i * i; i = 2.0 * r * i; r = t;
}
static __device__ inline void cmul(double& ar, double& ai, double br, double bi) {
    const double t = ar * br - ai * bi; ai = ar * bi + ai * br; ar = t;
}

// Grid (LSPLIT, HDIM). Thread tid owns l in [ls*LPB + 16*tid, +16).
// y_l = Re(2Cs w^l) obeys y_{l+2} = p2*y_l - q2*y_{l-2}; even/odd chains
// decouple. Mode PAIRS processed with forced v_pk_* (2 modes/inst).
//
// Prologue (fp64, in-block): ONE small-argument sincos + exp per thread;
// all large powers (w^16, w^64, w^256, w^1024, w^4096, base offsets) come
// from complex repeated squaring — avoids the fp64 large-argument sincos
// slow path (args were up to ~3e4 rad). Validated in round 1: absmax
// identical to the direct-sincos build (error ~1e-14 rel, invisible at fp32).
__global__ __launch_bounds__(BLOCK) void s4d_kernel(
    const float* __restrict__ C,          // (H, NH, 2)
    const float* __restrict__ log_dt,     // (H,)
    const float* __restrict__ log_A_real, // (H, NH)
    const float* __restrict__ A_imag,     // (H, NH)
    float* __restrict__ out)              // (H, LLEN)
{
    __shared__ float4 tabA[NP + 1][16];   // {Axa,Axb,Aya,Ayb}: 2Cs*exp(dtA*16lo)
    __shared__ float4 tabB[NP + 1][16];   // {Bxa,Bxb,Bya,Byb}: exp(dtA*(LPB*ls+256hi))
    __shared__ float4 s_w [NP + 1];       // {wra,wrb,wia,wib}
    __shared__ float4 s_pq[NP + 1];       // {pa,pb,qa,qb}
    __shared__ float4 s_p2[NP + 1];       // {p2a,p2b,q2a,q2b}

    const int h   = blockIdx.y;
    const int ls  = blockIdx.x;
    const int tid = threadIdx.x;

    // ---------------- prep (fp64): packed tables + constants ----------------
    {
        const int n = tid & 31;
        const int g = tid >> 5;            // 0..3 -> tabA, 4..7 -> tabB
        const int P = n >> 1, o = n & 1;
        const double dt  = exp((double)log_dt[h]);
        const double Are = -exp((double)log_A_real[h * NH + n]);
        const double Aim = (double)A_imag[h * NH + n];
        const double dre = Are * dt, dim = Aim * dt;

        double s1, c1; sincos(dim, &s1, &c1);   // |dim| <= ~9.8: fast path
        const double em  = exp(dre);
        const double w1r = em * c1, w1i = em * s1;

        // w^16 via 4 squarings
        double x16r = w1r, x16i = w1i;
#pragma unroll
        for (int j = 0; j < 4; ++j) csq(x16r, x16i);

        float* tabAf = (float*)&tabA[0][0];
        float* tabBf = (float*)&tabB[0][0];

        if (g < 4) {
            // 2*C_scaled (fp64)
            const double nre = w1r - 1.0, nim = w1i;
            const double inv = 1.0 / (Are * Are + Aim * Aim);
            const double fre = (nre * Are + nim * Aim) * inv;
            const double fim = (nim * Are - nre * Aim) * inv;
            const double Cre = (double)C[(h * NH + n) * 2 + 0];
            const double Cim = (double)C[(h * NH + n) * 2 + 1];
            double gr = 2.0 * (Cre * fre - Cim * fim);
            double gi = 2.0 * (Cre * fim + Cim * fre);

            // fold in w^(16*i0) = w^(64*g) = (w^64)^g
            double br = x16r, bi = x16i;       // w^16
            csq(br, bi); csq(br, bi);          // w^64
            if (g & 1) cmul(gr, gi, br, bi);   // bit0: w^64
            csq(br, bi);                       // w^128
            if (g & 2) cmul(gr, gi, br, bi);   // bit1: w^128

            const int i0 = g * 4;
#pragma unroll
            for (int k = 0; k < 4; ++k) {
                const int idx = (P * 16 + i0 + k) * 4;
                tabAf[idx + o]     = (float)gr;
                tabAf[idx + 2 + o] = (float)gi;
                cmul(gr, gi, x16r, x16i);      // step w^16
            }
        } else {
            // w^256 = (w^16)^16 via 4 more squarings
            double x256r = x16r, x256i = x16i;
#pragma unroll
            for (int j = 0; j < 4; ++j) csq(x256r, x256i);

            const int gg = g - 4;
            double er = 1.0, ei = 0.0;
            double br = x256r, bi = x256i;
            csq(br, bi); csq(br, bi);          // w^1024 = (w^256)^4
            if (gg & 1) cmul(er, ei, br, bi);  // bit0: w^1024
            csq(br, bi);                       // w^2048
            if (gg & 2) cmul(er, ei, br, bi);  // bit1: w^2048
            if (ls) {
                csq(br, bi);                   // w^4096
                cmul(er, ei, br, bi);
            }

            const int i0 = gg * 4;
#pragma unroll
            for (int k = 0; k < 4; ++k) {
                const int idx = (P * 16 + i0 + k) * 4;
                tabBf[idx + o]     = (float)er;
                tabBf[idx + 2 + o] = (float)ei;
                cmul(er, ei, x256r, x256i);    // step w^256
            }
        }

        if (g == 0) {
            float* wf  = (float*)&s_w[0];
            float* pqf = (float*)&s_pq[0];
            float* p2f = (float*)&s_p2[0];
            const double p  = 2.0 * w1r;
            const double q  = em * em;
            const double p2 = 2.0 * (w1r * w1r - w1i * w1i);
            const double q2 = q * q;
            wf [P * 4 + o]     = (float)w1r;
            wf [P * 4 + 2 + o] = (float)w1i;
            pqf[P * 4 + o]     = (float)p;
            pqf[P * 4 + 2 + o] = (float)q;
            p2f[P * 4 + o]     = (float)p2;
            p2f[P * 4 + 2 + o] = (float)q2;
        }
    }
    __syncthreads();

    const int lo = tid & 15, hi = tid >> 4;   // 16*tid = 256*hi + 16*lo

    vf2 acc[LPT];
#pragma unroll
    for (int l = 0; l < LPT; ++l) acc[l] = (vf2)(0.f);

    float4 a4 = tabA[0][lo], b4 = tabB[0][hi];
    float4 c0 = s_w[0], c1 = s_pq[0], c2 = s_p2[0];

#pragma unroll 2
    for (int P = 0; P < NP; ++P) {
        // prefetch next pair's LDS data (row NP is padding)
        const float4 na = tabA[P + 1][lo], nb = tabB[P + 1][hi];
        const float4 n0 = s_w[P + 1], n1 = s_pq[P + 1], n2 = s_p2[P + 1];

        const vf2 Ax = {a4.x, a4.y}, Ay = {a4.z, a4.w};
        const vf2 Bx = {b4.x, b4.y}, By = {b4.z, b4.w};
        const vf2 wr = {c0.x, c0.y}, wi = {c0.z, c0.w};
        const vf2 p  = {c1.x, c1.y}, q  = {c1.z, c1.w};
        const vf2 p2 = {c2.x, c2.y}, q2 = {c2.z, c2.w};

        // T = A'.B (Cs folded into A'); seeds y0..y3
        const vf2 Tr = pk_fms(Ax, Bx, pk_mul(Ay, By));
        const vf2 Ti = pk_fma(Ax, By, pk_mul(Ay, Bx));
        const vf2 y0 = Tr;
        const vf2 y1 = pk_fms(Tr, wr, pk_mul(Ti, wi));
        const vf2 y2 = pk_fms(p, y1, pk_mul(q, y0));
        const vf2 y3 = pk_fms(p, y2, pk_mul(q, y1));
        acc[0] = pk_add(acc[0], y0);
        acc[1] = pk_add(acc[1], y1);
        acc[2] = pk_add(acc[2], y2);
        acc[3] = pk_add(acc[3], y3);

        vf2 e0 = y0, e1 = y2, o0 = y1, o1 = y3;
#pragma unroll
        for (int m = 0; m < 6; ++m) {
            const vf2 e2 = pk_fms(p2, e1, pk_mul(q2, e0));
            const vf2 o2 = pk_fms(p2, o1, pk_mul(q2, o0));
            acc[4 + 2 * m] = pk_add(acc[4 + 2 * m], e2);
            acc[5 + 2 * m] = pk_add(acc[5 + 2 * m], o2);
            e0 = e1; e1 = e2;
            o0 = o1; o1 = o2;
        }
        a4 = na; b4 = nb; c0 = n0; c1 = n1; c2 = n2;
    }

    // epilogue: horizontal add over pair lanes, 4x float4 stores
    float* orow = out + (size_t)h * LLEN + ls * LPB + LPT * tid;
#pragma unroll
    for (int j = 0; j < 4; ++j) {
        *(float4*)(orow + 4 * j) = make_float4(
            acc[4*j+0].x + acc[4*j+0].y,
            acc[4*j+1].x + acc[4*j+1].y,
            acc[4*j+2].x + acc[4*j+2].y,
            acc[4*j+3].x + acc[4*j+3].y);
    }
}

extern "C" void kernel_launch(void* const* d_in, const int* in_sizes, int n_in,
                              void* d_out, int out_size, void* d_ws, size_t ws_size,
                              hipStream_t stream) {
    const float* C          = (const float*)d_in[0];
    const float* log_dt     = (const float*)d_in[1];
    const float* log_A_real = (const float*)d_in[2];
    const float* A_imag     = (const float*)d_in[3];
    float* out = (float*)d_out;

    dim3 grid(LSPLIT, HDIM);
    s4d_kernel<<<grid, BLOCK, 0, stream>>>(C, log_dt, log_A_real, A_imag, out);
}